// Round 8
// baseline (45.114 us; speedup 1.0000x reference)
//
#include <hip/hip_runtime.h>

#define C_     20
#define H_     64
#define W_     2048
#define HW_    (H_*W_)
#define KN     24          // 5x5 taps minus center
#define TH     8
#define TW     64
#define TR     (TH+4)      // 12
#define TC     (TW+4)      // 68
#define PLANE  (TR*TC)     // 816
#define DELEMS (C_*PLANE)  // 16320
#define DPAD   16384       // 32*512
#define NTHR   512
#define DSTG   32

#define GLOAD_LDS(SRC, DST)                                                     \
    __builtin_amdgcn_global_load_lds(                                           \
        (const __attribute__((address_space(1))) void*)(SRC),                   \
        (__attribute__((address_space(3))) void*)(DST), 4, 0, 0)

constexpr int KI[KN] = {0,0,0,0,0, 1,1,1,1,1, 2,2,2,2, 3,3,3,3,3, 4,4,4,4,4};
constexpr int KJ[KN] = {0,1,2,3,4, 0,1,2,3,4, 0,1,3,4, 0,1,2,3,4, 0,1,2,3,4};

__global__ __launch_bounds__(NTHR) void lp_kernel(
    const float* __restrict__ data,
    const float* __restrict__ mask,
    const float* __restrict__ bilat,
    const float* __restrict__ ang_w,
    const float* __restrict__ bi_w,
    const float* __restrict__ zbuf,
    float* __restrict__ out)
{
    __shared__ float s_data[DPAD];   // 64 KB, 20 class planes [cls][12][68]
    __shared__ float s_mask[1024];   // 4 KB

    const int tid = threadIdx.x;
    int bid = blockIdx.x;
    bid = (bid & 7)*64 + (bid >> 3);     // XCD swizzle (512 % 8 == 0, bijective)

    const int tx = bid & 31;
    const int ty = (bid >> 5) & 7;
    const int b  = bid >> 8;
    const int y0 = ty*TH, x0 = tx*TW;

    const float* dbase = data + (size_t)b*C_*HW_;
    const float* mbase = mask + (size_t)b*HW_;
    const int wbase = tid & ~63;

    // ---- async DMA: all 20 class planes (registers untouched) ----
#pragma unroll
    for (int s = 0; s < DSTG; ++s) {
        const int idx = tid + s*NTHR;
        const int cls = idx / PLANE;
        const int rem = idx - cls*PLANE;
        const int r   = rem / TC;
        const int col = rem - r*TC;
        const int gy = y0 + r - 2, gx = x0 + col - 2;
        const bool ok = (idx < DELEMS) & (gy >= 0) & (gy < H_) & (gx >= 0) & (gx < W_);
        const float* src = ok ? (dbase + (size_t)cls*HW_ + (gy*W_ + gx)) : zbuf;
        GLOAD_LDS(src, s_data + s*NTHR + wbase);
    }
    // ---- async DMA: mask tile ----
#pragma unroll
    for (int s = 0; s < 2; ++s) {
        const int idx = tid + s*NTHR;
        const int r   = idx / TC;
        const int col = idx - r*TC;
        const int gy = y0 + r - 2, gx = x0 + col - 2;
        const bool ok = (idx < PLANE) & (gy >= 0) & (gy < H_) & (gx >= 0) & (gx < W_);
        const float* src = ok ? (mbase + (gy*W_ + gx)) : zbuf;
        GLOAD_LDS(src, s_mask + s*NTHR + wbase);
    }

    const int lx  = tid & 63;
    const int lyy = tid >> 6;
    const int y = y0 + lyy, x = x0 + lx;

    __syncthreads();   // drains all DMA

    // mask taps -> registers (fits now: bb is only 6 live, biang eliminated)
    float mm[KN];
#pragma unroll
    for (int k = 0; k < KN; ++k) mm[k] = s_mask[(lyy + KI[k])*TC + (lx + KJ[k])];
    const float m_c = s_mask[(lyy + 2)*TC + (lx + 2)];

    float bi[C_];
#pragma unroll
    for (int c = 0; c < C_; ++c) bi[c] = 0.0f;

    float* aout = out + ((size_t)b*C_*H_ + y)*W_ + x;
    float* bout = aout + (size_t)2*C_*HW_;
    const float* bibase = bilat + (size_t)b*KN*HW_ + (size_t)y*W_ + x;

    // Residue-grouped class loop: classes cls === rg (mod 4) use ONLY the 6
    // bilateral planes j === rg (mod 4)  [since 20k mod 24 is a multiple of 4].
    // bb live: 24 -> 6 registers.
#pragma unroll
    for (int rg = 0; rg < 4; ++rg) {
        float bbsub[6];
#pragma unroll
        for (int u = 0; u < 6; ++u)
            bbsub[u] = bibase[(size_t)(rg + 4*u)*HW_];

#pragma unroll
        for (int t = 0; t < 5; ++t) {
            const int cls = rg + 4*t;
            float a = 0.0f, ba = 0.0f;
            const float* srow = s_data + cls*PLANE + lyy*TC + lx;
#pragma unroll
            for (int k = 0; k < KN; ++k) {
                const int i = KI[k], j = KJ[k];
                const float v = srow[i*TC + j];        // pairs -> ds_read2_b32
                a  += ang_w[cls*25 + i*5 + j] * v;     // wave-uniform -> s_load
                ba += bi_w [cls*25 + i*5 + j] * v;
                const int flat = k*C_ + cls;           // torch .view remap
                const int jj   = flat % KN;            // === rg (mod 4)
                bi[flat / KN] += bbsub[(jj - rg) / 4] * (v * mm[k]);
            }
            aout[(size_t)cls*HW_] = a;
            bout[(size_t)cls*HW_] = m_c * ba;          // PARTIAL: bi factor later
        }
    }

    // Drain stores, then reload partials and apply bi factor.
    // bout lines were never read before in this kernel -> no stale-L1 hazard;
    // the asm barrier forces a real reload (no store-forwarding) and orders it.
    asm volatile("s_waitcnt vmcnt(0)" ::: "memory");
#pragma unroll
    for (int c = 0; c < C_; ++c) {
        float p = bout[(size_t)c*HW_];
        bout[(size_t)c*HW_] = p * bi[c];
    }
}

extern "C" void kernel_launch(void* const* d_in, const int* in_sizes, int n_in,
                              void* d_out, int out_size, void* d_ws, size_t ws_size,
                              hipStream_t stream) {
    const float* data  = (const float*)d_in[0];
    const float* mask  = (const float*)d_in[1];
    const float* bilat = (const float*)d_in[2];
    const float* ang_w = (const float*)d_in[3];
    const float* bi_w  = (const float*)d_in[4];
    float* out = (float*)d_out;

    hipMemsetAsync(d_ws, 0, 256, stream);   // zero word for OOB halo lanes

    const int nblocks = 2 * (H_/TH) * (W_/TW);  // 512
    lp_kernel<<<nblocks, NTHR, 0, stream>>>(data, mask, bilat, ang_w, bi_w,
                                            (const float*)d_ws, out);
}